// Round 19
// baseline (177.487 us; speedup 1.0000x reference)
//
#include <hip/hip_runtime.h>

#define HW 256
#define HWMASK 255
#define CH 128
#define BATCH 8
#define NK 4

typedef float f32x4 __attribute__((ext_vector_type(4)));

// ---------------- Kernel A1: partial sums of guidance ----------------
__global__ __launch_bounds__(256) void mean1_kernel(const float* __restrict__ guid,
                                                    float* __restrict__ partial) {
    int blk = blockIdx.x;
    const float4* p = (const float4*)(guid + (size_t)blk * 16384);
    float s = 0.f;
    for (int i = threadIdx.x; i < 4096; i += 256) {
        float4 v = p[i];
        s += (v.x + v.y) + (v.z + v.w);
    }
    for (int off = 32; off; off >>= 1) s += __shfl_down(s, off, 64);
    __shared__ float red[4];
    if ((threadIdx.x & 63) == 0) red[threadIdx.x >> 6] = s;
    __syncthreads();
    if (threadIdx.x == 0) partial[blk] = (red[0] + red[1]) + (red[2] + red[3]);
}

// ---------------- Kernel B: finalize means + MLP + softmax ----------------
__global__ __launch_bounds__(256) void mlp_kernel(const float* __restrict__ partial,
                                                  const float* __restrict__ w1,
                                                  const float* __restrict__ b1,
                                                  const float* __restrict__ w2,
                                                  const float* __restrict__ b2,
                                                  float* __restrict__ wt) {
    __shared__ float gs[BATCH * CH];
    __shared__ float h1[BATCH * 32];
    __shared__ float lg[BATCH * NK];
    int t = threadIdx.x;
    for (int i = t; i < BATCH * CH; i += 256) {
        float4 v = *(const float4*)(partial + i * 4);
        gs[i] = ((v.x + v.y) + (v.z + v.w)) * (1.0f / 65536.0f);
    }
    __syncthreads();
    {
        int b = t >> 5, j = t & 31;
        float acc = b1[j];
        #pragma unroll 4
        for (int c = 0; c < CH; ++c) acc += gs[b * CH + c] * w1[j * CH + c];
        h1[b * 32 + j] = fmaxf(acc, 0.f);
    }
    __syncthreads();
    if (t < BATCH * NK) {
        int b = t >> 2, k = t & 3;
        float acc = b2[k];
        #pragma unroll
        for (int j = 0; j < 32; ++j) acc += h1[b * 32 + j] * w2[k * 32 + j];
        lg[b * NK + k] = acc;
    }
    __syncthreads();
    if (t < BATCH) {
        int b = t;
        float m = lg[b * 4];
        for (int k = 1; k < 4; ++k) m = fmaxf(m, lg[b * 4 + k]);
        float e[4], s = 0.f;
        for (int k = 0; k < 4; ++k) { e[k] = expf(lg[b * 4 + k] - m); s += e[k]; }
        float inv = 1.0f / s;
        for (int k = 0; k < 4; ++k) wt[b * 4 + k] = e[k] * inv;
    }
}

// ---------------- Kernel C: dyn = blend of basis filters, stored FLIPPED ----------------
__global__ __launch_bounds__(256) void dyn_kernel(const float* __restrict__ wt,
                                                  const float* __restrict__ basis,
                                                  float* __restrict__ dynF) {
    int idx = blockIdx.x * 256 + threadIdx.x;
    if (idx >= BATCH * CH * 49) return;
    int ij = idx % 49;
    int bc = idx / 49;
    int c = bc % CH;
    int b = bc / CH;
    float acc = 0.f;
    #pragma unroll
    for (int k = 0; k < NK; ++k)
        acc += wt[b * NK + k] * basis[(k * CH + c) * 49 + ij];
    dynF[bc * 49 + (48 - ij)] = acc;
}

// ---------------- Kernel D: circular depthwise 7x7 conv, column walker ----------------
// No LDS, no barriers. Block = 1 plane (4 waves x 64-row quarters); wave = 64
// lanes x 4 cols = full 256-px row, walks 70 input rows for 64 outputs (1.09x).
// Outer RUNTIME loop over 10 groups x inner UNROLLED 7 rows -> every acc/pf
// index compile-time (no alloca-promotion). Depth-7 prefetch (~3000 cy slack).
// Horizontal halo via cross-lane shuffle (circular wrap free via lane wrap).
__global__ __launch_bounds__(256) void conv_kernel(const float* __restrict__ x,
                                                   const float* __restrict__ dynF,
                                                   float* __restrict__ out) {
    int bc = blockIdx.x;                  // 0..1023 plane id
    const float* xp = x + (size_t)bc * (HW * HW);
    float* op = out + (size_t)bc * (HW * HW);
    int tid = threadIdx.x;
    int lane = tid & 63, ty = tid >> 6;
    int yb = ty * 64;                     // quarter start row

    // filter taps: block-uniform address -> scalar loads into SGPRs
    const float* df = dynF + bc * 49;
    float d[49];
    #pragma unroll
    for (int i = 0; i < 49; ++i) d[i] = df[i];

    int col = 4 * lane;                   // own quad: cols 4l..4l+3, 16B aligned
    int lL = (lane + 63) & 63;            // left neighbor lane (circular)
    int lR = (lane + 1) & 63;             // right neighbor lane (circular)

    // prologue: prefetch window rows 0..6 (abs yb-3 .. yb+3)
    float4 pf[7];
    #pragma unroll
    for (int p = 0; p < 7; ++p)
        pf[p] = *(const float4*)(xp + (((yb + p - 3) & HWMASK) * HW) + col);

    float acc[7][4] = {};

    #define ROWBODY(P, IIMAX, PREFROW, DOPREF, DOSTORE, OROW)                          \
        {                                                                              \
            float4 Q = pf[P];                                                          \
            if (DOPREF)                                                                \
                pf[P] = *(const float4*)(xp + (((PREFROW) & HWMASK) * HW) + col);      \
            float4 L, R;                                                               \
            L.x = __shfl(Q.x, lL, 64); L.y = __shfl(Q.y, lL, 64);                      \
            L.z = __shfl(Q.z, lL, 64); L.w = __shfl(Q.w, lL, 64);                      \
            R.x = __shfl(Q.x, lR, 64); R.y = __shfl(Q.y, lR, 64);                      \
            R.z = __shfl(Q.z, lR, 64); R.w = __shfl(Q.w, lR, 64);                      \
            float v[12] = {L.x, L.y, L.z, L.w, Q.x, Q.y, Q.z, Q.w, R.x, R.y, R.z, R.w};\
            _Pragma("unroll")                                                          \
            for (int ii = 0; ii <= (IIMAX); ++ii) {                                    \
                const int s = ((P) - ii + 7) % 7;                                      \
                _Pragma("unroll")                                                      \
                for (int q = 0; q < 4; ++q) {                                          \
                    _Pragma("unroll")                                                  \
                    for (int jj = 0; jj < 7; ++jj)                                     \
                        acc[s][q] += d[ii * 7 + jj] * v[q + jj + 1];                   \
                }                                                                      \
            }                                                                          \
            if (DOSTORE) {                                                             \
                const int s = ((P) + 1) % 7;                                           \
                f32x4 ov = {acc[s][0], acc[s][1], acc[s][2], acc[s][3]};               \
                __builtin_nontemporal_store(ov, (f32x4*)(op + (OROW) * HW + col));     \
                acc[s][0] = 0.f; acc[s][1] = 0.f; acc[s][2] = 0.f; acc[s][3] = 0.f;    \
            }                                                                          \
        }

    // group 0: rows i = p (abs yb-3+p); partial contributions (ii <= p); store only p=6 (o=0)
    #pragma unroll
    for (int p = 0; p < 7; ++p)
        ROWBODY(p, p, yb + 4 + p, 1, p == 6, yb);

    // groups 1..9: rows i = 7g+p; full contributions; store o = 7g+p-6 each step
    #pragma unroll 1
    for (int g = 1; g < 10; ++g) {
        int rowa = yb - 3 + 7 * g;        // abs input row at p=0
        #pragma unroll
        for (int p = 0; p < 7; ++p)
            ROWBODY(p, 6, rowa + 7 + p, g < 9, 1, yb + 7 * g + p - 6);
    }
    #undef ROWBODY
}

extern "C" void kernel_launch(void* const* d_in, const int* in_sizes, int n_in,
                              void* d_out, int out_size, void* d_ws, size_t ws_size,
                              hipStream_t stream) {
    const float* x        = (const float*)d_in[0];
    const float* guidance = (const float*)d_in[1];
    const float* basis    = (const float*)d_in[2];
    const float* w1       = (const float*)d_in[3];
    const float* b1       = (const float*)d_in[4];
    const float* w2       = (const float*)d_in[5];
    const float* b2       = (const float*)d_in[6];
    float* out = (float*)d_out;
    float* ws  = (float*)d_ws;

    float* partial = ws;                  // 4096
    float* wtb     = ws + 4096;           // 32
    float* dynF    = ws + 4096 + 32;      // 50176

    mean1_kernel<<<4096, 256, 0, stream>>>(guidance, partial);
    mlp_kernel<<<1, 256, 0, stream>>>(partial, w1, b1, w2, b2, wtb);
    dyn_kernel<<<(BATCH * CH * 49 + 255) / 256, 256, 0, stream>>>(wtb, basis, dynF);
    conv_kernel<<<BATCH * CH, 256, 0, stream>>>(x, dynF, out);
}

// Round 20
// 169.614 us; speedup vs baseline: 1.0464x; 1.0464x over previous
//
#include <hip/hip_runtime.h>

#define HW 256
#define HWMASK 255
#define CH 128
#define BATCH 8
#define NK 4
#define STRIP 16           // output rows per wave-strip
#define NIN (STRIP + 6)    // input rows per strip

typedef float f32x4 __attribute__((ext_vector_type(4)));

// ---------------- Kernel A1: partial sums of guidance ----------------
__global__ __launch_bounds__(256) void mean1_kernel(const float* __restrict__ guid,
                                                    float* __restrict__ partial) {
    int blk = blockIdx.x;
    const float4* p = (const float4*)(guid + (size_t)blk * 16384);
    float s = 0.f;
    for (int i = threadIdx.x; i < 4096; i += 256) {
        float4 v = p[i];
        s += (v.x + v.y) + (v.z + v.w);
    }
    for (int off = 32; off; off >>= 1) s += __shfl_down(s, off, 64);
    __shared__ float red[4];
    if ((threadIdx.x & 63) == 0) red[threadIdx.x >> 6] = s;
    __syncthreads();
    if (threadIdx.x == 0) partial[blk] = (red[0] + red[1]) + (red[2] + red[3]);
}

// ---------------- Kernel B: fused means+MLP+softmax+dyn-blend ----------------
// Every block redundantly computes the 8x4 softmax weights (tiny), then writes
// its 256-element slice of the flipped dynamic filters.
__global__ __launch_bounds__(256) void mlpdyn_kernel(const float* __restrict__ partial,
                                                     const float* __restrict__ w1,
                                                     const float* __restrict__ b1,
                                                     const float* __restrict__ w2,
                                                     const float* __restrict__ b2,
                                                     const float* __restrict__ basis,
                                                     float* __restrict__ dynF) {
    __shared__ float gs[BATCH * CH];
    __shared__ float h1[BATCH * 32];
    __shared__ float lg[BATCH * NK];
    __shared__ float wt[BATCH * NK];
    int t = threadIdx.x;
    for (int i = t; i < BATCH * CH; i += 256) {
        float4 v = *(const float4*)(partial + i * 4);
        gs[i] = ((v.x + v.y) + (v.z + v.w)) * (1.0f / 65536.0f);
    }
    __syncthreads();
    {
        int b = t >> 5, j = t & 31;
        float acc = b1[j];
        #pragma unroll 4
        for (int c = 0; c < CH; ++c) acc += gs[b * CH + c] * w1[j * CH + c];
        h1[b * 32 + j] = fmaxf(acc, 0.f);
    }
    __syncthreads();
    if (t < BATCH * NK) {
        int b = t >> 2, k = t & 3;
        float acc = b2[k];
        #pragma unroll
        for (int j = 0; j < 32; ++j) acc += h1[b * 32 + j] * w2[k * 32 + j];
        lg[b * NK + k] = acc;
    }
    __syncthreads();
    if (t < BATCH) {
        int b = t;
        float m = lg[b * 4];
        for (int k = 1; k < 4; ++k) m = fmaxf(m, lg[b * 4 + k]);
        float e[4], s = 0.f;
        for (int k = 0; k < 4; ++k) { e[k] = expf(lg[b * 4 + k] - m); s += e[k]; }
        float inv = 1.0f / s;
        for (int k = 0; k < 4; ++k) wt[b * 4 + k] = e[k] * inv;
    }
    __syncthreads();

    int idx = blockIdx.x * 256 + t;
    if (idx >= BATCH * CH * 49) return;
    int ij = idx % 49;
    int bc = idx / 49;
    int c = bc % CH;
    int b = bc / CH;
    float acc = 0.f;
    #pragma unroll
    for (int k = 0; k < NK; ++k)
        acc += wt[b * NK + k] * basis[(k * CH + c) * 49 + ij];
    dynF[bc * 49 + (48 - ij)] = acc;
}

// ---------------- Kernel D: circular depthwise 7x7 conv ----------------
// No LDS data path, no barriers. Wave = 64 lanes x 4 cols = full 256-px row.
// Horizontal halo via cross-lane shuffle of the neighbor quad (circular wrap
// comes free from lane wraparound). Vertical via 7 rolling accumulators.
// Depth-4 row prefetch (pf[i&3], static under full 22-iter unroll).
__global__ __launch_bounds__(256) void conv_kernel(const float* __restrict__ x,
                                                   const float* __restrict__ dynF,
                                                   float* __restrict__ out) {
    int bc = blockIdx.x;                  // 0..1023 plane id
    const float* xp = x + (size_t)bc * (HW * HW);
    float* op = out + (size_t)bc * (HW * HW);
    int tid = threadIdx.x;
    int lane = tid & 63, ty = tid >> 6;
    int yb = blockIdx.y * (4 * STRIP) + ty * STRIP;

    // filter taps: block-uniform address -> scalar loads into SGPRs
    const float* df = dynF + bc * 49;
    float d[49];
    #pragma unroll
    for (int i = 0; i < 49; ++i) d[i] = df[i];

    int col = 4 * lane;                   // own quad: cols 4l..4l+3, 16B aligned
    int lL = (lane + 63) & 63;            // left neighbor lane (circular)
    int lR = (lane + 1) & 63;             // right neighbor lane (circular)

    // prologue: prefetch input rows 0..3 of the window
    float4 pf[4];
    #pragma unroll
    for (int k = 0; k < 4; ++k)
        pf[k] = *(const float4*)(xp + (((yb + k - 3) & HWMASK) * HW) + col);

    float acc[7][4] = {};
    #pragma unroll
    for (int i = 0; i < NIN; ++i) {
        float4 Q = pf[i & 3];
        // reload this slot with row i+4 (lands while rows i..i+3 compute)
        if (i + 4 < NIN)
            pf[i & 3] = *(const float4*)(xp + (((yb + i + 1) & HWMASK) * HW) + col);

        // halo quads from neighbor lanes
        float4 L, R;
        L.x = __shfl(Q.x, lL, 64); L.y = __shfl(Q.y, lL, 64);
        L.z = __shfl(Q.z, lL, 64); L.w = __shfl(Q.w, lL, 64);
        R.x = __shfl(Q.x, lR, 64); R.y = __shfl(Q.y, lR, 64);
        R.z = __shfl(Q.z, lR, 64); R.w = __shfl(Q.w, lR, 64);
        float v[12] = {L.x, L.y, L.z, L.w, Q.x, Q.y, Q.z, Q.w, R.x, R.y, R.z, R.w};

        #pragma unroll
        for (int ii = 0; ii < 7; ++ii) {
            int o = i - ii;                       // output row receiving filter row ii
            if (o >= 0 && o < STRIP) {
                const int s = ((unsigned)o) % 7;  // compile-time under full unroll
                #pragma unroll
                for (int q = 0; q < 4; ++q) {
                    #pragma unroll
                    for (int jj = 0; jj < 7; ++jj)
                        acc[s][q] += d[ii * 7 + jj] * v[q + jj + 1];
                }
            }
        }
        if (i >= 6) {
            const int o = i - 6;
            const int s = ((unsigned)o) % 7;
            f32x4 ov = {acc[s][0], acc[s][1], acc[s][2], acc[s][3]};
            __builtin_nontemporal_store(ov, (f32x4*)(op + (yb + o) * HW + col));
            acc[s][0] = 0.f; acc[s][1] = 0.f; acc[s][2] = 0.f; acc[s][3] = 0.f;
        }
    }
}

extern "C" void kernel_launch(void* const* d_in, const int* in_sizes, int n_in,
                              void* d_out, int out_size, void* d_ws, size_t ws_size,
                              hipStream_t stream) {
    const float* x        = (const float*)d_in[0];
    const float* guidance = (const float*)d_in[1];
    const float* basis    = (const float*)d_in[2];
    const float* w1       = (const float*)d_in[3];
    const float* b1       = (const float*)d_in[4];
    const float* w2       = (const float*)d_in[5];
    const float* b2       = (const float*)d_in[6];
    float* out = (float*)d_out;
    float* ws  = (float*)d_ws;

    float* partial = ws;                  // 4096
    float* dynF    = ws + 4096;           // 50176

    mean1_kernel<<<4096, 256, 0, stream>>>(guidance, partial);
    mlpdyn_kernel<<<(BATCH * CH * 49 + 255) / 256, 256, 0, stream>>>(partial, w1, b1, w2, b2, basis, dynF);
    conv_kernel<<<dim3(BATCH * CH, HW / (4 * STRIP)), 256, 0, stream>>>(x, dynF, out);
}